// Round 13
// baseline (196.230 us; speedup 1.0000x reference)
//
#include <hip/hip_runtime.h>
#include <hip/hip_bf16.h>
#include <math.h>

// B=2, C=128, H=W=64, heads=4, head_dim=32, kernel=7 (49 taps), depth=2.
// Inputs fp32, OUTPUT fp32. Intermediates bf16. MFMA GEMMs.
// R13 = R12 with the attn_proj grid fixed: 256 tiles (16x16 of 4x4), not 512.
#define PIX 8192
typedef __hip_bfloat16 bf16;
typedef __attribute__((ext_vector_type(8))) short short8;
typedef __attribute__((ext_vector_type(4))) float f32x4;

__device__ inline float bflo(unsigned u) { return __uint_as_float(u << 16); }
__device__ inline float bfhi(unsigned u) { return __uint_as_float(u & 0xffff0000u); }
__device__ inline unsigned short f2b(float f) {
  __hip_bfloat16 h = __float2bfloat16(f);
  return *reinterpret_cast<unsigned short*>(&h);
}
__device__ inline unsigned pack2(float a, float b) {
  return (unsigned)f2b(a) | ((unsigned)f2b(b) << 16);
}

// ---------- prep: transpose x -> y(bf16, NHWC) AND cvt weights to bf16 ----------
__global__ __launch_bounds__(256) void prep(const float* __restrict__ x,
                                            const float* __restrict__ qw,
                                            const float* __restrict__ pw,
                                            unsigned short* __restrict__ y,
                                            unsigned short* __restrict__ wq,
                                            unsigned short* __restrict__ wp) {
  int tid = threadIdx.x;
  if (blockIdx.x >= 128) {                     // weight convert: 384 blocks
    int idx = (blockIdx.x - 128) * 256 + tid;
    if (idx < 98304) wq[idx] = f2b(qw[idx]);
    if (idx < 32768) wp[idx] = f2b(pw[idx]);
    return;
  }
  __shared__ float tile[64][129];
  int blk = blockIdx.x;                        // b*64 + i
  int b = blk >> 6, i = blk & 63;
  const float* xbase = x + (size_t)b * 128 * 4096 + (size_t)i * 64;
  for (int idx = tid; idx < 8192; idx += 256) {
    int c = idx >> 6, j = idx & 63;
    tile[j][c] = xbase[(size_t)c * 4096 + j];
  }
  __syncthreads();
  unsigned short* yrow = y + (size_t)blk * 64 * 128;
  for (int idx = tid; idx < 8192; idx += 256) {
    int j = idx >> 7, c = idx & 127;
    yrow[idx] = f2b(tile[j][c]);
  }
}

// ---------- MFMA GEMM (qkv): C[M,384] = A[M,128] * W[384,128]^T + bias ----------
__global__ __launch_bounds__(256) void gemm_mfma(const unsigned short* __restrict__ A,
                                                 const unsigned short* __restrict__ W,
                                                 const float* __restrict__ bias,
                                                 unsigned short* __restrict__ Cmat,
                                                 int N) {
  int m0 = blockIdx.x * 64, n0 = blockIdx.y * 64;
  int tid = threadIdx.x;
  int w = tid >> 6, lane = tid & 63;
  int quad = lane >> 4, l16 = lane & 15;

  const short8* ap =
      (const short8*)(A + (size_t)(m0 + w * 16 + l16) * 128 + quad * 8);
  short8 a[4];
#pragma unroll
  for (int kc = 0; kc < 4; ++kc) a[kc] = ap[kc * 4];

  f32x4 acc[4];
#pragma unroll
  for (int nt = 0; nt < 4; ++nt) {
    const short8* bp =
        (const short8*)(W + (size_t)(n0 + nt * 16 + l16) * 128 + quad * 8);
    f32x4 c = {0.f, 0.f, 0.f, 0.f};
#pragma unroll
    for (int kc = 0; kc < 4; ++kc)
      c = __builtin_amdgcn_mfma_f32_16x16x32_bf16(a[kc], bp[kc * 4], c, 0, 0, 0);
    acc[nt] = c;
  }

#pragma unroll
  for (int nt = 0; nt < 4; ++nt) {
    int col = n0 + nt * 16 + l16;
    float bv = bias[col];
#pragma unroll
    for (int r = 0; r < 4; ++r) {
      int m = m0 + w * 16 + quad * 4 + r;
      Cmat[(size_t)m * N + col] = f2b(acc[nt][r] + bv);
    }
  }
}

// ---------- fused neighborhood attention + proj ----------
// grid (256 tiles, 2 batch) = 512 blocks; block 256 = 4 waves.
// Attention: thread = (px=tid>>4 of 4x4 tile, h=(tid>>2)&3, r=tid&3 -> 8 dims).
// Halo 10x10, all 4 heads staged; row stride 136 ushorts (<=2-way aliasing).
// Proj: attention out (16px x 128ch bf16) staged in LDS, then in-block MFMA
// GEMM M=16,N=128,K=128 (wave w -> cols [32w,32w+32)), bias, write y.
#define ASTRIDE 136
__global__ __launch_bounds__(256, 2) void attn_proj(const unsigned short* __restrict__ qkvp,
                                                    const float* __restrict__ rpb,
                                                    const unsigned short* __restrict__ wp,
                                                    const float* __restrict__ pb,
                                                    unsigned short* __restrict__ yout) {
  __shared__ __align__(16) unsigned short kbuf[100 * ASTRIDE];
  __shared__ __align__(16) unsigned short vbuf[100 * ASTRIDE];
  __shared__ __align__(16) unsigned short po[16 * ASTRIDE];
  __shared__ float rb[676];

  int ti = blockIdx.x >> 4, tj = blockIdx.x & 15;   // 16x16 tiles of 4x4 px
  int bz = blockIdx.y;
  int tid = threadIdx.x;
  int bi0 = ti * 4 - 3, bj0 = tj * 4 - 3;           // halo origin (10x10)

  for (int t = tid; t < 676; t += 256) rb[t] = rpb[t];

  // stage K/V halo: 100 px x 32 chunks of 16B (16 K + 16 V; 4 heads x 32 d)
  for (int t = tid; t < 3200; t += 256) {
    int row = t >> 5;            // 0..99
    int sub = t & 31;
    int isv = sub >> 4;          // 0=K, 1=V
    int c = sub & 15;            // chunk within 128-ushort slice
    int ri = row / 10, rj = row - ri * 10;
    int gi = bi0 + ri, gj = bj0 + rj;
    uint4 val = make_uint4(0, 0, 0, 0);
    if ((unsigned)gi < 64u && (unsigned)gj < 64u) {
      int pixn = (bz * 64 + gi) * 64 + gj;
      val = *(const uint4*)(qkvp + (size_t)pixn * 384 + 128 + isv * 128 + c * 8);
    }
    *(uint4*)((isv ? vbuf : kbuf) + row * ASTRIDE + c * 8) = val;
  }
  __syncthreads();

  {
    int r = tid & 3;               // dim quad (8 dims)
    int h = (tid >> 2) & 3;        // head
    int px = tid >> 4;             // 0..15
    int pi = px >> 2, pj = px & 3;
    int i = ti * 4 + pi, j = tj * 4 + pj;
    int si = min(max(i - 3, 0), 57), sj = min(max(j - 3, 0), 57);
    int li = si - bi0, lj = sj - bj0;
    int oi = i - si, oj = j - sj;
    int pix = (bz * 64 + i) * 64 + j;

    const float scale = 0.17677669529663687f;   // 32^-0.5
    float q[8];
    {
      uint4 t = *(const uint4*)(qkvp + (size_t)pix * 384 + h * 32 + r * 8);
      q[0] = bflo(t.x) * scale;  q[1] = bfhi(t.x) * scale;
      q[2] = bflo(t.y) * scale;  q[3] = bfhi(t.y) * scale;
      q[4] = bflo(t.z) * scale;  q[5] = bfhi(t.z) * scale;
      q[6] = bflo(t.w) * scale;  q[7] = bfhi(t.w) * scale;
    }

    const unsigned short* kh = kbuf + h * 32 + r * 8;
    const unsigned short* vh = vbuf + h * 32 + r * 8;
    const float* rbh = rb + h * 169;

    float s49[49];
#pragma unroll
    for (int p = 0; p < 7; ++p) {
#pragma unroll
      for (int qq = 0; qq < 7; ++qq) {
        int n = (li + p) * 10 + (lj + qq);
        uint4 t = *(const uint4*)(kh + n * ASTRIDE);
        float dot = q[0] * bflo(t.x) + q[1] * bfhi(t.x)
                  + q[2] * bflo(t.y) + q[3] * bfhi(t.y)
                  + q[4] * bflo(t.z) + q[5] * bfhi(t.z)
                  + q[6] * bflo(t.w) + q[7] * bfhi(t.w);
        dot += __shfl_xor(dot, 1);
        dot += __shfl_xor(dot, 2);
        s49[p * 7 + qq] = dot + rbh[(p + 6 - oi) * 13 + (qq + 6 - oj)];
      }
    }

    float m = s49[0];
#pragma unroll
    for (int t = 1; t < 49; ++t) m = fmaxf(m, s49[t]);
    float sum = 0.f;
#pragma unroll
    for (int t = 0; t < 49; ++t) { s49[t] = __expf(s49[t] - m); sum += s49[t]; }
    float inv = 1.f / sum;

    float acc[8] = {0.f, 0.f, 0.f, 0.f, 0.f, 0.f, 0.f, 0.f};
#pragma unroll
    for (int p = 0; p < 7; ++p) {
#pragma unroll
      for (int qq = 0; qq < 7; ++qq) {
        float w = s49[p * 7 + qq];
        int n = (li + p) * 10 + (lj + qq);
        uint4 t = *(const uint4*)(vh + n * ASTRIDE);
        acc[0] += w * bflo(t.x);  acc[1] += w * bfhi(t.x);
        acc[2] += w * bflo(t.y);  acc[3] += w * bfhi(t.y);
        acc[4] += w * bflo(t.z);  acc[5] += w * bfhi(t.z);
        acc[6] += w * bflo(t.w);  acc[7] += w * bfhi(t.w);
      }
    }
    uint4 t;
    t.x = pack2(acc[0] * inv, acc[1] * inv);
    t.y = pack2(acc[2] * inv, acc[3] * inv);
    t.z = pack2(acc[4] * inv, acc[5] * inv);
    t.w = pack2(acc[6] * inv, acc[7] * inv);
    *(uint4*)(po + px * ASTRIDE + h * 32 + r * 8) = t;
  }
  __syncthreads();

  // proj: M=16 (po rows), N=128, K=128. wave w -> cols [32w, 32w+32).
  {
    int w = tid >> 6, lane = tid & 63;
    int quad = lane >> 4, l16 = lane & 15;
    short8 a[4];
#pragma unroll
    for (int kc = 0; kc < 4; ++kc)
      a[kc] = *(const short8*)(po + l16 * ASTRIDE + kc * 32 + quad * 8);
#pragma unroll
    for (int nt = 0; nt < 2; ++nt) {
      int col = w * 32 + nt * 16 + l16;
      const short8* bp = (const short8*)(wp + (size_t)col * 128 + quad * 8);
      f32x4 c = {0.f, 0.f, 0.f, 0.f};
#pragma unroll
      for (int kc = 0; kc < 4; ++kc)
        c = __builtin_amdgcn_mfma_f32_16x16x32_bf16(a[kc], bp[kc * 4], c, 0, 0, 0);
      float bv = pb[col];
#pragma unroll
      for (int r2 = 0; r2 < 4; ++r2) {
        int m = quad * 4 + r2;               // po row = tile pixel
        int i = ti * 4 + (m >> 2), j = tj * 4 + (m & 3);
        int pixm = (bz * 64 + i) * 64 + j;
        yout[(size_t)pixm * 128 + col] = f2b(c[r2] + bv);
      }
    }
  }
}

// ---------- LayerNorm over C + transpose to (B,C,H,W), fp32 store ----------
__global__ __launch_bounds__(256) void ln_out(const unsigned short* __restrict__ y,
                                              const float* __restrict__ g,
                                              const float* __restrict__ bta,
                                              float* __restrict__ out) {
  __shared__ float tile[64][129];
  __shared__ float mean_s[64], rstd_s[64];
  int blk = blockIdx.x;
  int b = blk >> 6, i = blk & 63;
  int tid = threadIdx.x;
  const unsigned short* yrow = y + (size_t)blk * 64 * 128;
  for (int idx = tid; idx < 8192; idx += 256) {
    int j = idx >> 7, c = idx & 127;
    tile[j][c] = __uint_as_float((unsigned)yrow[idx] << 16);
  }
  __syncthreads();
  int jj = tid >> 2, qtr = tid & 3;
  float sum = 0.f, sumsq = 0.f;
#pragma unroll
  for (int cc = 0; cc < 32; ++cc) {
    float v = tile[jj][qtr * 32 + cc];
    sum += v; sumsq += v * v;
  }
  sum += __shfl_xor(sum, 1);  sum += __shfl_xor(sum, 2);
  sumsq += __shfl_xor(sumsq, 1);  sumsq += __shfl_xor(sumsq, 2);
  if (qtr == 0) {
    float mu = sum * (1.f / 128.f);
    mean_s[jj] = mu;
    rstd_s[jj] = rsqrtf(sumsq * (1.f / 128.f) - mu * mu + 1e-5f);
  }
  __syncthreads();
  int c0 = tid >> 6;
  int j = tid & 63;
  for (int c = c0; c < 128; c += 4) {
    float v = (tile[j][c] - mean_s[j]) * rstd_s[j] * g[c] + bta[c];
    out[(((size_t)b * 128 + c) * 64 + i) * 64 + j] = v;
  }
}

extern "C" void kernel_launch(void* const* d_in, const int* in_sizes, int n_in,
                              void* d_out, int out_size, void* d_ws, size_t ws_size,
                              hipStream_t stream) {
  (void)in_sizes; (void)n_in; (void)out_size; (void)ws_size;
  const float* x   = (const float*)d_in[0];
  const float* qw  = (const float*)d_in[1];   // (2,384,128)
  const float* qb  = (const float*)d_in[2];   // (2,384)
  const float* rpb = (const float*)d_in[3];   // (2,4,13,13)
  const float* pw  = (const float*)d_in[4];   // (2,128,128)
  const float* pb  = (const float*)d_in[5];   // (2,128)
  const float* lg  = (const float*)d_in[6];
  const float* lb  = (const float*)d_in[7];

  unsigned short* y    = (unsigned short*)d_ws;          // PIX*128 (2 MB)
  unsigned short* qkv  = y + (size_t)PIX * 128;          // PIX*384 (6 MB)
  unsigned short* wq   = qkv + (size_t)PIX * 384;        // 98304
  unsigned short* wp   = wq + 98304;                     // 32768
  float* out = (float*)d_out;

  prep<<<512, 256, 0, stream>>>(x, qw, pw, y, wq, wp);
  for (int l = 0; l < 2; ++l) {
    gemm_mfma<<<dim3(128, 6), 256, 0, stream>>>(y, wq + l * 49152, qb + l * 384, qkv, 384);
    attn_proj<<<dim3(256, 2), 256, 0, stream>>>(qkv, rpb + l * 676,
                                                wp + l * 16384, pb + l * 128, y);
  }
  ln_out<<<128, 256, 0, stream>>>(y, lg, lb, out);
}

// Round 14
// 146.650 us; speedup vs baseline: 1.3381x; 1.3381x over previous
//
#include <hip/hip_runtime.h>
#include <hip/hip_bf16.h>
#include <math.h>

// B=2, C=128, H=W=64, heads=4, head_dim=32, kernel=7 (49 taps), depth=2.
// Inputs fp32, OUTPUT fp32. Intermediates bf16. MFMA GEMMs (LDS-free).
// R14 = R11 pipeline (separate attn + proj) + prep fusion + na_attn v6:
// scores kept in LDS (not registers) -> ~40 live VGPRs, no scratch spill.
#define PIX 8192
typedef __hip_bfloat16 bf16;
typedef __attribute__((ext_vector_type(8))) short short8;
typedef __attribute__((ext_vector_type(4))) float f32x4;

__device__ inline float bflo(unsigned u) { return __uint_as_float(u << 16); }
__device__ inline float bfhi(unsigned u) { return __uint_as_float(u & 0xffff0000u); }
__device__ inline unsigned short f2b(float f) {
  __hip_bfloat16 h = __float2bfloat16(f);
  return *reinterpret_cast<unsigned short*>(&h);
}
__device__ inline unsigned pack2(float a, float b) {
  return (unsigned)f2b(a) | ((unsigned)f2b(b) << 16);
}

// ---------- prep: transpose x -> y(bf16, NHWC) AND cvt weights to bf16 ----------
__global__ __launch_bounds__(256) void prep(const float* __restrict__ x,
                                            const float* __restrict__ qw,
                                            const float* __restrict__ pw,
                                            unsigned short* __restrict__ y,
                                            unsigned short* __restrict__ wq,
                                            unsigned short* __restrict__ wp) {
  int tid = threadIdx.x;
  if (blockIdx.x >= 128) {                     // weight convert: 384 blocks
    int idx = (blockIdx.x - 128) * 256 + tid;
    if (idx < 98304) wq[idx] = f2b(qw[idx]);
    if (idx < 32768) wp[idx] = f2b(pw[idx]);
    return;
  }
  __shared__ float tile[64][129];
  int blk = blockIdx.x;                        // b*64 + i
  int b = blk >> 6, i = blk & 63;
  const float* xbase = x + (size_t)b * 128 * 4096 + (size_t)i * 64;
  for (int idx = tid; idx < 8192; idx += 256) {
    int c = idx >> 6, j = idx & 63;
    tile[j][c] = xbase[(size_t)c * 4096 + j];
  }
  __syncthreads();
  unsigned short* yrow = y + (size_t)blk * 64 * 128;
  for (int idx = tid; idx < 8192; idx += 256) {
    int j = idx >> 7, c = idx & 127;
    yrow[idx] = f2b(tile[j][c]);
  }
}

// ---------- MFMA GEMM: C[M,N] = A[M,128] * W[N,128]^T + bias ----------
__global__ __launch_bounds__(256) void gemm_mfma(const unsigned short* __restrict__ A,
                                                 const unsigned short* __restrict__ W,
                                                 const float* __restrict__ bias,
                                                 unsigned short* __restrict__ Cmat,
                                                 int N) {
  int m0 = blockIdx.x * 64, n0 = blockIdx.y * 64;
  int tid = threadIdx.x;
  int w = tid >> 6, lane = tid & 63;
  int quad = lane >> 4, l16 = lane & 15;

  const short8* ap =
      (const short8*)(A + (size_t)(m0 + w * 16 + l16) * 128 + quad * 8);
  short8 a[4];
#pragma unroll
  for (int kc = 0; kc < 4; ++kc) a[kc] = ap[kc * 4];

  f32x4 acc[4];
#pragma unroll
  for (int nt = 0; nt < 4; ++nt) {
    const short8* bp =
        (const short8*)(W + (size_t)(n0 + nt * 16 + l16) * 128 + quad * 8);
    f32x4 c = {0.f, 0.f, 0.f, 0.f};
#pragma unroll
    for (int kc = 0; kc < 4; ++kc)
      c = __builtin_amdgcn_mfma_f32_16x16x32_bf16(a[kc], bp[kc * 4], c, 0, 0, 0);
    acc[nt] = c;
  }

#pragma unroll
  for (int nt = 0; nt < 4; ++nt) {
    int col = n0 + nt * 16 + l16;
    float bv = bias[col];
#pragma unroll
    for (int r = 0; r < 4; ++r) {
      int m = m0 + w * 16 + quad * 4 + r;
      Cmat[(size_t)m * N + col] = f2b(acc[nt][r] + bv);
    }
  }
}

// ---------- neighborhood attention v6 ----------
// grid (128 tiles, 2 head-pairs, 2 batch) = 512 blocks; block 256 = 4 waves.
// tile = 8 rows x 4 cols; halo 14 x 10 = 140 px; 2 heads (2hp, 2hp+1) staged.
// thread: r=tid&3 (8 dims), hl=(tid>>2)&1 (local head), px=tid>>3 (0..31).
// v6: the 49 scores live in LDS sc[ph][52] (quad-lane 0 writes), softmax is
// a max pass + fused exp/sum/PV pass -> ~40 live VGPRs, no scratch spill.
#define RSTRIDE 72
__global__ __launch_bounds__(256, 2) void na_attn(const unsigned short* __restrict__ qkvp,
                                                  const float* __restrict__ rpb,
                                                  unsigned short* __restrict__ out) {
  __shared__ __align__(16) unsigned short kbuf[140 * RSTRIDE];
  __shared__ __align__(16) unsigned short vbuf[140 * RSTRIDE];
  __shared__ float rb[338];
  __shared__ float sc[64][52];

  int ti = blockIdx.x >> 4, tj = blockIdx.x & 15;   // 8 x 16 tiles of 8x4 px
  int hp = blockIdx.y;
  int bz = blockIdx.z;
  int tid = threadIdx.x;
  int bi0 = ti * 8 - 3, bj0 = tj * 4 - 3;           // halo origin

  for (int t = tid; t < 338; t += 256) rb[t] = rpb[hp * 338 + t];

  // stage K/V halo: 140 px x 16 chunks of 16B (8 K + 8 V; 2 heads x 32 dims)
  for (int t = tid; t < 2240; t += 256) {
    int row = t >> 4;            // 0..139
    int sub = t & 15;
    int isv = sub >> 3;          // 0=K, 1=V
    int c = sub & 7;             // chunk within the 2-head slice (64 ushorts)
    int ri = row / 10, rj = row - ri * 10;
    int gi = bi0 + ri, gj = bj0 + rj;
    uint4 val = make_uint4(0, 0, 0, 0);
    if ((unsigned)gi < 64u && (unsigned)gj < 64u) {
      int pixn = (bz * 64 + gi) * 64 + gj;
      val = *(const uint4*)(qkvp + (size_t)pixn * 384 + 128 + isv * 128 +
                            hp * 64 + c * 8);
    }
    *(uint4*)((isv ? vbuf : kbuf) + row * RSTRIDE + c * 8) = val;
  }
  __syncthreads();

  int r = tid & 3;               // dim quad (8 dims)
  int hl = (tid >> 2) & 1;       // local head
  int px = tid >> 3;             // 0..31
  int ph = px * 2 + hl;          // pixel-head slot 0..63
  int pi = px >> 2, pj = px & 3;
  int i = ti * 8 + pi, j = tj * 4 + pj;
  int si = min(max(i - 3, 0), 57), sj = min(max(j - 3, 0), 57);
  int li = si - bi0, lj = sj - bj0;
  int oi = i - si, oj = j - sj;
  int H = hp * 2 + hl;
  int pix = (bz * 64 + i) * 64 + j;

  const float scale = 0.17677669529663687f;   // 32^-0.5
  float q[8];
  {
    uint4 t = *(const uint4*)(qkvp + (size_t)pix * 384 + H * 32 + r * 8);
    q[0] = bflo(t.x) * scale;  q[1] = bfhi(t.x) * scale;
    q[2] = bflo(t.y) * scale;  q[3] = bfhi(t.y) * scale;
    q[4] = bflo(t.z) * scale;  q[5] = bfhi(t.z) * scale;
    q[6] = bflo(t.w) * scale;  q[7] = bfhi(t.w) * scale;
  }

  const unsigned short* kh = kbuf + hl * 32 + r * 8;
  const unsigned short* vh = vbuf + hl * 32 + r * 8;
  const float* rbh = rb + hl * 169;

  // scores -> LDS: 8-dim partial dot, quad butterfly, lane r==0 stores
#pragma unroll
  for (int p = 0; p < 7; ++p) {
#pragma unroll
    for (int qq = 0; qq < 7; ++qq) {
      int n = (li + p) * 10 + (lj + qq);
      uint4 t = *(const uint4*)(kh + n * RSTRIDE);
      float dot = q[0] * bflo(t.x) + q[1] * bfhi(t.x)
                + q[2] * bflo(t.y) + q[3] * bfhi(t.y)
                + q[4] * bflo(t.z) + q[5] * bfhi(t.z)
                + q[6] * bflo(t.w) + q[7] * bfhi(t.w);
      dot += __shfl_xor(dot, 1);
      dot += __shfl_xor(dot, 2);
      if (r == 0) sc[ph][p * 7 + qq] = dot + rbh[(p + 6 - oi) * 13 + (qq + 6 - oj)];
    }
  }
  __syncthreads();

  // pass 1: max
  float m = -INFINITY;
#pragma unroll
  for (int n = 0; n < 49; ++n) m = fmaxf(m, sc[ph][n]);

  // pass 2: fused exp/sum + P@V over this lane's 8 dims
  float sum = 0.f;
  float acc[8] = {0.f, 0.f, 0.f, 0.f, 0.f, 0.f, 0.f, 0.f};
#pragma unroll
  for (int p = 0; p < 7; ++p) {
#pragma unroll
    for (int qq = 0; qq < 7; ++qq) {
      float e = __expf(sc[ph][p * 7 + qq] - m);
      sum += e;
      int n = (li + p) * 10 + (lj + qq);
      uint4 t = *(const uint4*)(vh + n * RSTRIDE);
      acc[0] += e * bflo(t.x);  acc[1] += e * bfhi(t.x);
      acc[2] += e * bflo(t.y);  acc[3] += e * bfhi(t.y);
      acc[4] += e * bflo(t.z);  acc[5] += e * bfhi(t.z);
      acc[6] += e * bflo(t.w);  acc[7] += e * bfhi(t.w);
    }
  }
  float inv = 1.f / sum;
  uint4 t;
  t.x = pack2(acc[0] * inv, acc[1] * inv);
  t.y = pack2(acc[2] * inv, acc[3] * inv);
  t.z = pack2(acc[4] * inv, acc[5] * inv);
  t.w = pack2(acc[6] * inv, acc[7] * inv);
  *(uint4*)(out + (size_t)pix * 128 + H * 32 + r * 8) = t;
}

// ---------- LayerNorm over C + transpose to (B,C,H,W), fp32 store ----------
__global__ __launch_bounds__(256) void ln_out(const unsigned short* __restrict__ y,
                                              const float* __restrict__ g,
                                              const float* __restrict__ bta,
                                              float* __restrict__ out) {
  __shared__ float tile[64][129];
  __shared__ float mean_s[64], rstd_s[64];
  int blk = blockIdx.x;
  int b = blk >> 6, i = blk & 63;
  int tid = threadIdx.x;
  const unsigned short* yrow = y + (size_t)blk * 64 * 128;
  for (int idx = tid; idx < 8192; idx += 256) {
    int j = idx >> 7, c = idx & 127;
    tile[j][c] = __uint_as_float((unsigned)yrow[idx] << 16);
  }
  __syncthreads();
  int jj = tid >> 2, qtr = tid & 3;
  float sum = 0.f, sumsq = 0.f;
#pragma unroll
  for (int cc = 0; cc < 32; ++cc) {
    float v = tile[jj][qtr * 32 + cc];
    sum += v; sumsq += v * v;
  }
  sum += __shfl_xor(sum, 1);  sum += __shfl_xor(sum, 2);
  sumsq += __shfl_xor(sumsq, 1);  sumsq += __shfl_xor(sumsq, 2);
  if (qtr == 0) {
    float mu = sum * (1.f / 128.f);
    mean_s[jj] = mu;
    rstd_s[jj] = rsqrtf(sumsq * (1.f / 128.f) - mu * mu + 1e-5f);
  }
  __syncthreads();
  int c0 = tid >> 6;
  int j = tid & 63;
  for (int c = c0; c < 128; c += 4) {
    float v = (tile[j][c] - mean_s[j]) * rstd_s[j] * g[c] + bta[c];
    out[(((size_t)b * 128 + c) * 64 + i) * 64 + j] = v;
  }
}

extern "C" void kernel_launch(void* const* d_in, const int* in_sizes, int n_in,
                              void* d_out, int out_size, void* d_ws, size_t ws_size,
                              hipStream_t stream) {
  (void)in_sizes; (void)n_in; (void)out_size; (void)ws_size;
  const float* x   = (const float*)d_in[0];
  const float* qw  = (const float*)d_in[1];   // (2,384,128)
  const float* qb  = (const float*)d_in[2];   // (2,384)
  const float* rpb = (const float*)d_in[3];   // (2,4,13,13)
  const float* pw  = (const float*)d_in[4];   // (2,128,128)
  const float* pb  = (const float*)d_in[5];   // (2,128)
  const float* lg  = (const float*)d_in[6];
  const float* lb  = (const float*)d_in[7];

  unsigned short* y    = (unsigned short*)d_ws;          // PIX*128 (2 MB)
  unsigned short* qkv  = y + (size_t)PIX * 128;          // PIX*384 (6 MB)
  unsigned short* wq   = qkv + (size_t)PIX * 384;        // 98304
  unsigned short* wp   = wq + 98304;                     // 32768
  unsigned short* attn = (unsigned short*)d_out;         // PIX*128 (scratch)
  float* out = (float*)d_out;

  prep<<<512, 256, 0, stream>>>(x, qw, pw, y, wq, wp);
  for (int l = 0; l < 2; ++l) {
    gemm_mfma<<<dim3(128, 6), 256, 0, stream>>>(y, wq + l * 49152, qb + l * 384, qkv, 384);
    na_attn<<<dim3(128, 2, 2), 256, 0, stream>>>(qkv, rpb + l * 676, attn);
    gemm_mfma<<<dim3(128, 2), 256, 0, stream>>>(attn, wp + l * 16384, pb + l * 128, y, 128);
  }
  ln_out<<<128, 256, 0, stream>>>(y, lg, lb, out);
}